// Round 1
// baseline (489.597 us; speedup 1.0000x reference)
//
#include <hip/hip_runtime.h>

#define BATCH 65536

typedef float f32x4 __attribute__((ext_vector_type(4)));
typedef _Float16 f16x8 __attribute__((ext_vector_type(8)));

__device__ __forceinline__ float act_f(float x, float a0, float a1, float a2,
                                       float a3, float a4) {
  float ax = fabsf(x);
  float e = __builtin_amdgcn_exp2f(ax * -2.8853900817779268f);
  float th = (1.0f - e) * __builtin_amdgcn_rcpf(1.0f + e);
  th = copysignf(th, x);
  float arg = fmaf(a1, x, a2);
  float rev = arg * 0.15915494309189535f;
  rev -= floorf(rev);
  float s = __builtin_amdgcn_sinf(rev);
  return fmaf(a3, x, fmaf(a0 * th, s, a4));
}

// split + transpose weights: W[K][N] fp32 -> Wt_hi/lo[N][K] fp16
__global__ __launch_bounds__(256) void splitT_k(const float* __restrict__ W,
                                                _Float16* __restrict__ hi,
                                                _Float16* __restrict__ lo,
                                                int K, int N) {
  const int i = blockIdx.x * 256 + threadIdx.x;
  if (i >= K * N) return;
  const int k = i / N, n = i % N;
  const float w = W[i];
  const _Float16 h = (_Float16)w;
  hi[(size_t)n * K + k] = h;
  lo[(size_t)n * K + k] = (_Float16)(w - (float)h);
}

__device__ __forceinline__ f32x4 mfma3(f16x8 ah, f16x8 al, f16x8 bh, f16x8 bl,
                                       f32x4 c) {
  c = __builtin_amdgcn_mfma_f32_16x16x32_f16(ah, bh, c, 0, 0, 0);
  c = __builtin_amdgcn_mfma_f32_16x16x32_f16(ah, bl, c, 0, 0, 0);
  c = __builtin_amdgcn_mfma_f32_16x16x32_f16(al, bh, c, 0, 0, 0);
  return c;
}

// Fully fused 3-layer MLP + softmax. One block = 64 batch rows, 512 threads
// (8 waves as 1m x 8n: no B-fragment duplication across waves -> weight L2
// traffic = 2 MB/block). All intermediates stay in LDS:
//   h1 hi/lo planes [64][512] fp16 (128 KB, XOR-swizzled)
//   h2 panel hi/lo [64][128] fp16 (32 KB), 4 panels, each consumed
//   immediately by a partial GEMM3 accumulation into registers.
// 3-product fp16 hi/lo compensation everywhere (identical numerics to the
// previous multi-kernel pipeline). Softmax fused in-block (blocks own full
// 256-col rows).
__global__ __launch_bounds__(512, 2) void fused_mlp(
    const float* __restrict__ data, const _Float16* __restrict__ w1h,
    const _Float16* __restrict__ w1l, const _Float16* __restrict__ w2h,
    const _Float16* __restrict__ w2l, const _Float16* __restrict__ w3h,
    const _Float16* __restrict__ w3l, const float* __restrict__ b1,
    const float* __restrict__ p1, const float* __restrict__ b2,
    const float* __restrict__ p2, const float* __restrict__ b3,
    const float* __restrict__ p3, float* __restrict__ out) {
  __shared__ __align__(16) char smem[163840];
  char* const h2hB = smem + 131072;  // [64][128] fp16 hi
  char* const h2lB = smem + 147456;  // [64][128] fp16 lo

  const int tid = threadIdx.x;
  const int wv = tid >> 6;
  const int lane = tid & 63;
  const int m16 = lane & 15;
  const int quad = lane >> 4;
  const int kq = quad * 8;
  const int row0 = blockIdx.x * 64;

  const f32x4 zero = {0.f, 0.f, 0.f, 0.f};

  // ---------------- Phase 1: h1 = act(data @ W1 + b1) -> LDS ----------------
  {
    f32x4 acc[4][4];
#pragma unroll
    for (int i = 0; i < 4; ++i)
#pragma unroll
      for (int j = 0; j < 4; ++j) acc[i][j] = zero;

#pragma unroll
    for (int kt = 0; kt < 8; ++kt) {
      const int k = kt * 32 + kq;
      f16x8 ah[4], al[4];
#pragma unroll
      for (int tm = 0; tm < 4; ++tm) {
        const float* pa = data + (size_t)(row0 + tm * 16 + m16) * 256 + k;
        const f32x4 x0 = *(const f32x4*)pa;
        const f32x4 x1 = *(const f32x4*)(pa + 4);
#pragma unroll
        for (int j = 0; j < 4; ++j) {
          const _Float16 g0 = (_Float16)x0[j];
          ah[tm][j] = g0;
          al[tm][j] = (_Float16)(x0[j] - (float)g0);
          const _Float16 g1 = (_Float16)x1[j];
          ah[tm][4 + j] = g1;
          al[tm][4 + j] = (_Float16)(x1[j] - (float)g1);
        }
      }
#pragma unroll
      for (int tn = 0; tn < 4; ++tn) {
        const int col = wv * 64 + tn * 16 + m16;
        const f16x8 bh = *(const f16x8*)(w1h + col * 256 + k);
        const f16x8 bl = *(const f16x8*)(w1l + col * 256 + k);
#pragma unroll
        for (int tm = 0; tm < 4; ++tm)
          acc[tm][tn] = mfma3(ah[tm], al[tm], bh, bl, acc[tm][tn]);
      }
    }
    // epilogue: bias+act, split to fp16 hi/lo, swizzled LDS write
#pragma unroll
    for (int tn = 0; tn < 4; ++tn) {
      const int col = wv * 64 + tn * 16 + m16;
      const float bs = b1[col];
      const float q0 = p1[col * 5 + 0], q1 = p1[col * 5 + 1],
                  q2 = p1[col * 5 + 2], q3 = p1[col * 5 + 3],
                  q4 = p1[col * 5 + 4];
#pragma unroll
      for (int tm = 0; tm < 4; ++tm) {
#pragma unroll
        for (int r = 0; r < 4; ++r) {
          const int row = tm * 16 + quad * 4 + r;
          const float y = act_f(acc[tm][tn][r] + bs, q0, q1, q2, q3, q4);
          const _Float16 h = (_Float16)y;
          const _Float16 l = (_Float16)(y - (float)h);
          const int off = ((row << 10) + (col << 1)) ^ ((row & 7) << 4);
          *(_Float16*)(smem + off) = h;
          *(_Float16*)(smem + 65536 + off) = l;
        }
      }
    }
  }
  __syncthreads();

  // ------- Phase 2+3: per 128-col panel: h2p = act(h1@W2), acc3 += h2p@W3 ---
  f32x4 acc3[4][2];
#pragma unroll
  for (int i = 0; i < 4; ++i) {
    acc3[i][0] = zero;
    acc3[i][1] = zero;
  }

#pragma unroll 1
  for (int p = 0; p < 4; ++p) {
    f32x4 acc2[4];
#pragma unroll
    for (int i = 0; i < 4; ++i) acc2[i] = zero;
    const int colw = p * 128 + wv * 16 + m16;  // this thread's W2 column
#pragma unroll
    for (int kt = 0; kt < 16; ++kt) {
      const int k = kt * 32 + kq;
      const f16x8 bh = *(const f16x8*)(w2h + (size_t)colw * 512 + k);
      const f16x8 bl = *(const f16x8*)(w2l + (size_t)colw * 512 + k);
#pragma unroll
      for (int tm = 0; tm < 4; ++tm) {
        const int row = tm * 16 + m16;
        const int off = ((row << 10) + (k << 1)) ^ ((row & 7) << 4);
        const f16x8 ah = *(const f16x8*)(smem + off);
        const f16x8 al = *(const f16x8*)(smem + 65536 + off);
        acc2[tm] = mfma3(ah, al, bh, bl, acc2[tm]);
      }
    }
    __syncthreads();  // previous panel's GEMM3 reads are done
    {
      const float bs = b2[colw];
      const float q0 = p2[colw * 5 + 0], q1 = p2[colw * 5 + 1],
                  q2 = p2[colw * 5 + 2], q3 = p2[colw * 5 + 3],
                  q4 = p2[colw * 5 + 4];
      const int cl = wv * 16 + m16;
#pragma unroll
      for (int tm = 0; tm < 4; ++tm) {
#pragma unroll
        for (int r = 0; r < 4; ++r) {
          const int row = tm * 16 + quad * 4 + r;
          const float y = act_f(acc2[tm][r] + bs, q0, q1, q2, q3, q4);
          const _Float16 h = (_Float16)y;
          const _Float16 l = (_Float16)(y - (float)h);
          const int off = ((row << 8) + (cl << 1)) ^ ((row & 7) << 4);
          *(_Float16*)(h2hB + off) = h;
          *(_Float16*)(h2lB + off) = l;
        }
      }
    }
    __syncthreads();  // h2 panel ready
    // GEMM3 partial accumulation, K slice [p*128, p*128+128)
#pragma unroll
    for (int kt = 0; kt < 4; ++kt) {
      const int kl = kt * 32 + kq;
      f16x8 ah[4], al[4];
#pragma unroll
      for (int tm = 0; tm < 4; ++tm) {
        const int row = tm * 16 + m16;
        const int off = ((row << 8) + (kl << 1)) ^ ((row & 7) << 4);
        ah[tm] = *(const f16x8*)(h2hB + off);
        al[tm] = *(const f16x8*)(h2lB + off);
      }
#pragma unroll
      for (int tn = 0; tn < 2; ++tn) {
        const int col = wv * 32 + tn * 16 + m16;
        const f16x8 bh =
            *(const f16x8*)(w3h + (size_t)col * 512 + p * 128 + kl);
        const f16x8 bl =
            *(const f16x8*)(w3l + (size_t)col * 512 + p * 128 + kl);
#pragma unroll
        for (int tm = 0; tm < 4; ++tm)
          acc3[tm][tn] = mfma3(ah[tm], al[tm], bh, bl, acc3[tm][tn]);
      }
    }
  }
  __syncthreads();  // last GEMM3 reads done; h2 region reusable as scratch

  // ---------------- fused softmax over 256 cols per row ----------------
  float* const red = (float*)(smem + 131072);            // [8][64] partials
  float* const rowred = (float*)(smem + 131072 + 2048);  // [64]

  float y[4][2][4];
#pragma unroll
  for (int tn = 0; tn < 2; ++tn) {
    const int col = wv * 32 + tn * 16 + m16;
    const float bs = b3[col];
    const float q0 = p3[col * 5 + 0], q1 = p3[col * 5 + 1],
                q2 = p3[col * 5 + 2], q3 = p3[col * 5 + 3],
                q4 = p3[col * 5 + 4];
#pragma unroll
    for (int tm = 0; tm < 4; ++tm)
#pragma unroll
      for (int r = 0; r < 4; ++r)
        y[tm][tn][r] = act_f(acc3[tm][tn][r] + bs, q0, q1, q2, q3, q4);
  }
  // wave-local row max over its 32 cols (tn pair + 16 m16 lanes)
  float mx[4][4];
#pragma unroll
  for (int tm = 0; tm < 4; ++tm)
#pragma unroll
    for (int r = 0; r < 4; ++r) {
      float m = fmaxf(y[tm][0][r], y[tm][1][r]);
#pragma unroll
      for (int off = 1; off < 16; off <<= 1) m = fmaxf(m, __shfl_xor(m, off));
      mx[tm][r] = m;
    }
  if (m16 == 0) {
#pragma unroll
    for (int tm = 0; tm < 4; ++tm)
#pragma unroll
      for (int r = 0; r < 4; ++r)
        red[wv * 64 + tm * 16 + quad * 4 + r] = mx[tm][r];
  }
  __syncthreads();
  if (tid < 64) {
    float m = red[tid];
#pragma unroll
    for (int w = 1; w < 8; ++w) m = fmaxf(m, red[w * 64 + tid]);
    rowred[tid] = m;
  }
  __syncthreads();
  float sm[4][4];
#pragma unroll
  for (int tm = 0; tm < 4; ++tm)
#pragma unroll
    for (int r = 0; r < 4; ++r) {
      const float m = rowred[tm * 16 + quad * 4 + r];
      float s = 0.f;
#pragma unroll
      for (int tn = 0; tn < 2; ++tn) {
        const float e =
            __builtin_amdgcn_exp2f((y[tm][tn][r] - m) * 1.4426950408889634f);
        y[tm][tn][r] = e;
        s += e;
      }
#pragma unroll
      for (int off = 1; off < 16; off <<= 1) s += __shfl_xor(s, off);
      sm[tm][r] = s;
    }
  if (m16 == 0) {
#pragma unroll
    for (int tm = 0; tm < 4; ++tm)
#pragma unroll
      for (int r = 0; r < 4; ++r)
        red[wv * 64 + tm * 16 + quad * 4 + r] = sm[tm][r];
  }
  __syncthreads();
  if (tid < 64) {
    float s = red[tid];
#pragma unroll
    for (int w = 1; w < 8; ++w) s += red[w * 64 + tid];
    rowred[tid] = __builtin_amdgcn_rcpf(s);
  }
  __syncthreads();
#pragma unroll
  for (int tm = 0; tm < 4; ++tm)
#pragma unroll
    for (int r = 0; r < 4; ++r) {
      const int row = tm * 16 + quad * 4 + r;
      const float inv = rowred[row];
#pragma unroll
      for (int tn = 0; tn < 2; ++tn) {
        const int col = wv * 32 + tn * 16 + m16;
        out[(size_t)(row0 + row) * 256 + col] = y[tm][tn][r] * inv;
      }
    }
}

extern "C" void kernel_launch(void* const* d_in, const int* in_sizes, int n_in,
                              void* d_out, int out_size, void* d_ws,
                              size_t ws_size, hipStream_t stream) {
  const float* data = (const float*)d_in[0];
  const float* W1 = (const float*)d_in[1];
  const float* b1 = (const float*)d_in[2];
  const float* a1 = (const float*)d_in[3];
  const float* W2 = (const float*)d_in[4];
  const float* b2 = (const float*)d_in[5];
  const float* a2 = (const float*)d_in[6];
  const float* W3 = (const float*)d_in[7];
  const float* b3 = (const float*)d_in[8];
  const float* a3 = (const float*)d_in[9];

  char* ws = (char*)d_ws;
  const size_t KB = 1024;
  _Float16* w1h = (_Float16*)(ws + 0 * KB);     // [512][256]
  _Float16* w1l = (_Float16*)(ws + 256 * KB);
  _Float16* w2h = (_Float16*)(ws + 512 * KB);   // [512][512]
  _Float16* w2l = (_Float16*)(ws + 1024 * KB);
  _Float16* w3h = (_Float16*)(ws + 1536 * KB);  // [256][512]
  _Float16* w3l = (_Float16*)(ws + 1792 * KB);

  splitT_k<<<(256 * 512 + 255) / 256, 256, 0, stream>>>(W1, w1h, w1l, 256, 512);
  splitT_k<<<(512 * 512 + 255) / 256, 256, 0, stream>>>(W2, w2h, w2l, 512, 512);
  splitT_k<<<(512 * 256 + 255) / 256, 256, 0, stream>>>(W3, w3h, w3l, 512, 256);

  fused_mlp<<<BATCH / 64, 512, 0, stream>>>(data, w1h, w1l, w2h, w2l, w3h, w3l,
                                            b1, a1, b2, a2, b3, a3,
                                            (float*)d_out);
}